// Round 5
// baseline (173.919 us; speedup 1.0000x reference)
//
#include <hip/hip_runtime.h>
#include <hip/hip_bf16.h>
#include <stdint.h>

// VQ: x [N=131072, D=64] fp32, E [D=64, K=1024] fp32.
// R10: stage B tiles through LDS via global_load_lds (m97 pattern). R9 showed
// register-held B prefetch from L2 can't cover latency at 2 waves/SIMD: all 4
// waves load IDENTICAL B frags (lane-only indexed) -> 4x redundant L2 traffic
// on latency-exposed chains. Now: per tile, 256 threads each issue ONE 16B
// global_load_lds (tile = 4KB contiguous in the fragment-linear Bhi/Blo
// tables) into a double buffer; frags come from ds_read_b128 (16B/lane,
// conflict-free). One __syncthreads per tile is the only drain; staged loads
// have the whole body to land. L2 B-traffic drops 4x.
// Wave-uniform LDS base + per-lane global src per m104/m108.
// Screen math + fused fp64 refine identical to R8/R9.
// Verified facts used: A[m=lane&15][k=(lane>>4)*8+j] (m89/m91/m120),
// C/D col=lane&15 row=(lane>>4)*4+reg (m89/m91), frag types short8/float4.

typedef unsigned long long u64;
typedef short short8 __attribute__((ext_vector_type(8)));
typedef float f32x4 __attribute__((ext_vector_type(4)));

constexpr int D = 64;
constexpr int K = 1024;
constexpr float TAU = 1e-3f;

__device__ __forceinline__ unsigned short bf16_rne(float v) {
    uint32_t u = __float_as_uint(v);
    uint32_t r = u + 0x7FFFu + ((u >> 16) & 1u);
    return (unsigned short)(r >> 16);
}
__device__ __forceinline__ float bf16_f(unsigned short h) {
    return __uint_as_float(((uint32_t)h) << 16);
}
// monotone fp32 -> u32 map (min preserved) — R3-proven
__device__ __forceinline__ uint32_t fmap(float v) {
    uint32_t u = __float_as_uint(v);
    return (u & 0x80000000u) ? ~u : (u | 0x80000000u);
}
__device__ __forceinline__ float funmap(uint32_t m) {
    uint32_t u = (m & 0x80000000u) ? (m ^ 0x80000000u) : ~m;
    return __uint_as_float(u);
}
__device__ __forceinline__ void top2_merge(u64& b, u64& s, u64 ob, u64 os) {
    if (ob < b) { s = (b < os) ? b : os; b = ob; }
    else        { s = (ob < s) ? ob : s; }
}
__device__ __forceinline__ u64 shfl_xor_u64(u64 v, int m) {
    uint32_t lo = (uint32_t)v, hi = (uint32_t)(v >> 32);
    lo = (uint32_t)__shfl_xor((int)lo, m, 64);
    hi = (uint32_t)__shfl_xor((int)hi, m, 64);
    return ((u64)hi << 32) | lo;
}
__device__ __forceinline__ double shfl_xor_f64(double v, int m) {
    int lo = __double2loint(v), hi = __double2hiint(v);
    lo = __shfl_xor(lo, m, 64);
    hi = __shfl_xor(hi, m, 64);
    return __hiloint2double(hi, lo);
}
// 8 fp32 -> bf16 hi + residual-lo fragments (in-register, no LDS transpose)
__device__ __forceinline__ void cvt8(float4 a, float4 b, short8& H, short8& L) {
    float v[8] = {a.x, a.y, a.z, a.w, b.x, b.y, b.z, b.w};
    #pragma unroll
    for (int e = 0; e < 8; ++e) {
        unsigned short h = bf16_rne(v[e]);
        H[e] = (short)h;
        L[e] = (short)bf16_rne(v[e] - bf16_f(h));
    }
}

// ---- prep: e_sq (f64/f32), ET[k][d] gather table, Bhi/Blo fragment-linear
//      bf16 tables of -2E (hi + residual lo). grid 256 x 256. ----
__global__ __launch_bounds__(256) void vq_prep(const float* __restrict__ E,
                                               double* __restrict__ e_sq64,
                                               float* __restrict__ e_sq32,
                                               float* __restrict__ ET,
                                               unsigned short* __restrict__ Bhi,
                                               unsigned short* __restrict__ Blo) {
    int tid = blockIdx.x * 256 + threadIdx.x;        // 0..65535
    if (tid < K) {
        int k = tid;
        double s = 0.0;
        for (int d = 0; d < D; ++d) {
            float v = E[d * K + k];
            s = fma((double)v, (double)v, s);
            ET[k * D + d] = v;
        }
        e_sq64[k] = s;
        e_sq32[k] = (float)s;
    }
    // table entry: frag f = t*2+c (t=tile 0..63, c=k-chunk 0..1), lane l, slot j
    //   value = -2*E[d][code], d = 32c + 8*(l>>4) + j, code = 16t + (l&15)
    //   linear: tile t owns shorts [t*1024, t*1024+1024), chunk c at +c*512,
    //   lane l at +l*8 — 4KB/tile contiguous across Bhi+Blo.
    {
        int j = tid & 7;
        int l = (tid >> 3) & 63;
        int f = tid >> 9;            // 0..127
        int c = f & 1;
        int t = f >> 1;
        int d = 32 * c + 8 * (l >> 4) + j;
        int code = 16 * t + (l & 15);
        float v = -2.0f * E[d * K + code];
        unsigned short h = bf16_rne(v);
        Bhi[tid] = h;
        Blo[tid] = bf16_rne(v - bf16_f(h));
    }
}

// ---- screen + fused exact refine: block = 128 rows (4 waves x 32) ----
__global__ __launch_bounds__(256, 4) void vq_screen(
    const float* __restrict__ x,
    const unsigned short* __restrict__ Bhi, const unsigned short* __restrict__ Blo,
    const float* __restrict__ e_sq32, const double* __restrict__ e_sq64,
    const float* __restrict__ ET, float* __restrict__ out) {
    __shared__ float esq[K];                   // 4 KB
    __shared__ unsigned short Bst[2][2048];    // 8 KB double-buffered B tile
    __shared__ int bk[128];                    // 0.5 KB
    __shared__ double xs64[D];                 // 0.5 KB (refine staging)
    __shared__ double wbv[4];
    __shared__ int wbk_s[4];
    __shared__ int flag_list[128];             // 0.5 KB
    __shared__ int flag_n;

    const int t0 = threadIdx.x;
    const int base = blockIdx.x * 128;

    if (t0 == 0) flag_n = 0;

    // stage e_sq
    #pragma unroll
    for (int i = 0; i < 4; ++i) esq[i * 256 + t0] = e_sq32[i * 256 + t0];

    const int wid = t0 >> 6, l = t0 & 63;
    const int col = l & 15, quad = l >> 4;

    // B-tile staging setup: wave wid stages 1KB (64 lanes x 16B).
    //   waves 0,1 -> hi half [0,1024) shorts; waves 2,3 -> lo half [1024,2048).
    //   LDS dest base is wave-uniform (+lane*16 applied by HW);
    //   global src is per-lane: table + t*1024 + (wid&1)*512 + l*8 shorts.
    const unsigned short* stage_src =
        ((wid < 2) ? Bhi : Blo) + (wid & 1) * 512 + l * 8;
    const int stage_dst = (wid & 2) * 512 + (wid & 1) * 512;   // shorts offset
    #define STAGE_B(tile, buf)                                                   \
        __builtin_amdgcn_global_load_lds(                                        \
            (const __attribute__((address_space(1))) void*)(stage_src + (tile) * 1024), \
            (__attribute__((address_space(3))) void*)&Bst[buf][stage_dst],       \
            16, 0, 0)

    // A fragments for 2 rowsets, loaded DIRECTLY from global in fragment order
    // (verified layout: m = lane&15, k = quad*8 + j, k-chunks at 0 and 32).
    const int gr0 = base + wid * 32 + col;     // rowset a global row
    short8 Ah0a, Ah1a, Al0a, Al1a, Ah0b, Ah1b, Al0b, Al1b;
    {
        const float* xr = x + (size_t)gr0 * D + quad * 8;
        float4 p0 = *(const float4*)(xr);
        float4 p1 = *(const float4*)(xr + 4);
        float4 p2 = *(const float4*)(xr + 32);
        float4 p3 = *(const float4*)(xr + 36);
        const float* xs = xr + 16 * D;         // rowset b
        float4 q0 = *(const float4*)(xs);
        float4 q1 = *(const float4*)(xs + 4);
        float4 q2 = *(const float4*)(xs + 32);
        float4 q3 = *(const float4*)(xs + 36);
        cvt8(p0, p1, Ah0a, Al0a);
        cvt8(p2, p3, Ah1a, Al1a);
        cvt8(q0, q1, Ah0b, Al0b);
        cvt8(q2, q3, Ah1b, Al1b);
    }

    float besta[4], seca[4], bestb[4], secb[4];
    int bidxa[4], bidxb[4];
    #pragma unroll
    for (int r = 0; r < 4; ++r) {
        besta[r] = 3.4e38f; seca[r] = 3.4e38f; bidxa[r] = 0;
        bestb[r] = 3.4e38f; secb[r] = 3.4e38f; bidxb[r] = 0;
    }

    // prologue: stage tile 0 into buf 0; barrier drains it (esq too)
    STAGE_B(0, 0);
    __syncthreads();

    for (int t = 0; t < 64; ++t) {
        const int cbuf = t & 1, nbuf = cbuf ^ 1;
        // stage next tile (t=63 wraps to tile 0 into buf0 — unread, harmless;
        // prior barrier guarantees buf0's readers are done)
        STAGE_B((t + 1) & 63, nbuf);

        // B frags from LDS (16B/lane contiguous — conflict-free ds_read_b128)
        short8 bh0 = *(const short8*)&Bst[cbuf][l * 8];
        short8 bh1 = *(const short8*)&Bst[cbuf][512 + l * 8];
        short8 bl0 = *(const short8*)&Bst[cbuf][1024 + l * 8];
        short8 bl1 = *(const short8*)&Bst[cbuf][1536 + l * 8];
        float esv = esq[t * 16 + col];           // same addr across quads -> broadcast

        f32x4 Ca = {esv, esv, esv, esv};
        f32x4 Cb = {esv, esv, esv, esv};
        // single chain per rowset; a/b chains independent -> ILP for the pipe
        Ca = __builtin_amdgcn_mfma_f32_16x16x32_bf16(Ah0a, bh0, Ca, 0, 0, 0);
        Cb = __builtin_amdgcn_mfma_f32_16x16x32_bf16(Ah0b, bh0, Cb, 0, 0, 0);
        Ca = __builtin_amdgcn_mfma_f32_16x16x32_bf16(Ah1a, bh1, Ca, 0, 0, 0);
        Cb = __builtin_amdgcn_mfma_f32_16x16x32_bf16(Ah1b, bh1, Cb, 0, 0, 0);
        Ca = __builtin_amdgcn_mfma_f32_16x16x32_bf16(Ah0a, bl0, Ca, 0, 0, 0);
        Cb = __builtin_amdgcn_mfma_f32_16x16x32_bf16(Ah0b, bl0, Cb, 0, 0, 0);
        Ca = __builtin_amdgcn_mfma_f32_16x16x32_bf16(Ah1a, bl1, Ca, 0, 0, 0);
        Cb = __builtin_amdgcn_mfma_f32_16x16x32_bf16(Ah1b, bl1, Cb, 0, 0, 0);
        Ca = __builtin_amdgcn_mfma_f32_16x16x32_bf16(Al0a, bh0, Ca, 0, 0, 0);
        Cb = __builtin_amdgcn_mfma_f32_16x16x32_bf16(Al0b, bh0, Cb, 0, 0, 0);
        Ca = __builtin_amdgcn_mfma_f32_16x16x32_bf16(Al1a, bh1, Ca, 0, 0, 0);
        Cb = __builtin_amdgcn_mfma_f32_16x16x32_bf16(Al1b, bh1, Cb, 0, 0, 0);

        int tc = t * 16;
        #pragma unroll
        for (int r = 0; r < 4; ++r) {
            float va = Ca[r];
            bool lta = va < besta[r];
            float mxa = fmaxf(va, besta[r]);
            besta[r] = fminf(va, besta[r]);
            seca[r]  = fminf(seca[r], mxa);
            bidxa[r] = lta ? tc : bidxa[r];
            float vb = Cb[r];
            bool ltb = vb < bestb[r];
            float mxb = fmaxf(vb, bestb[r]);
            bestb[r] = fminf(vb, bestb[r]);
            secb[r]  = fminf(secb[r], mxb);
            bidxb[r] = ltb ? tc : bidxb[r];
        }
        // drain: next tile's staging landed; all waves done reading cbuf
        __syncthreads();
    }
    #undef STAGE_B

    // per-register reduce across the 16 col-lanes (masks 1..8 preserve quad)
    #pragma unroll
    for (int r = 0; r < 4; ++r) {
        {   // rowset a
            u64 b = ((u64)fmap(besta[r]) << 32) | (uint32_t)(bidxa[r] + col);
            u64 s = ((u64)fmap(seca[r]) << 32) | 0xFFFFFFFFu;
            #pragma unroll
            for (int m = 8; m >= 1; m >>= 1) {
                u64 ob = shfl_xor_u64(b, m);
                u64 os = shfl_xor_u64(s, m);
                top2_merge(b, s, ob, os);
            }
            if (col == 0) {
                int rowL = wid * 32 + quad * 4 + r;       // verified C row map
                bk[rowL] = (int)(uint32_t)(b & 0xFFFFFFFFu);
                float vb = funmap((uint32_t)(b >> 32));
                float vs = funmap((uint32_t)(s >> 32));
                if (vs - vb < TAU) {
                    int idx = atomicAdd(&flag_n, 1);
                    flag_list[idx] = rowL;
                }
            }
        }
        {   // rowset b
            u64 b = ((u64)fmap(bestb[r]) << 32) | (uint32_t)(bidxb[r] + col);
            u64 s = ((u64)fmap(secb[r]) << 32) | 0xFFFFFFFFu;
            #pragma unroll
            for (int m = 8; m >= 1; m >>= 1) {
                u64 ob = shfl_xor_u64(b, m);
                u64 os = shfl_xor_u64(s, m);
                top2_merge(b, s, ob, os);
            }
            if (col == 0) {
                int rowL = wid * 32 + 16 + quad * 4 + r;
                bk[rowL] = (int)(uint32_t)(b & 0xFFFFFFFFu);
                float vb = funmap((uint32_t)(b >> 32));
                float vs = funmap((uint32_t)(s >> 32));
                if (vs - vb < TAU) {
                    int idx = atomicAdd(&flag_n, 1);
                    flag_list[idx] = rowL;
                }
            }
        }
    }
    __syncthreads();

    // fused exact refine for flagged rows (rare: ~0.03 rows/block expected).
    // Identical math + tie-breaks to the proven vq_refine kernel:
    // ET[k*D+d] == E[d*K+k] exactly; fp64 fma over ascending d; v<best with
    // ascending k; wave reduce then cross-wave lowest-k-on-tie merge.
    {
        int nf = flag_n;                         // uniform across block
        for (int f = 0; f < nf; ++f) {
            int rowR = flag_list[f];
            if (t0 < D) xs64[t0] = (double)x[(size_t)(base + rowR) * D + t0];
            __syncthreads();
            double best = 1.0e300; int bestk = 0;
            #pragma unroll
            for (int j = 0; j < 4; ++j) {
                int k = t0 * 4 + j;
                const float* ep = ET + (size_t)k * D;
                double a = 0.0;
                #pragma unroll 4
                for (int d = 0; d < D; ++d)
                    a = fma(xs64[d], (double)ep[d], a);
                double v = fma(-2.0, a, e_sq64[k]);
                if (v < best) { best = v; bestk = k; }
            }
            #pragma unroll
            for (int m = 32; m >= 1; m >>= 1) {
                double ov = shfl_xor_f64(best, m);
                int    ok = __shfl_xor(bestk, m, 64);
                if (ov < best || (ov == best && ok < bestk)) { best = ov; bestk = ok; }
            }
            if ((t0 & 63) == 0) { wbv[t0 >> 6] = best; wbk_s[t0 >> 6] = bestk; }
            __syncthreads();
            if (t0 == 0) {
                double bv = wbv[0]; int bb = wbk_s[0];
                for (int w = 1; w < 4; ++w)
                    if (wbv[w] < bv || (wbv[w] == bv && wbk_s[w] < bb)) { bv = wbv[w]; bb = wbk_s[w]; }
                bk[rowR] = bb;
            }
            __syncthreads();
        }
    }

    // gather: thread t0 copies 128 B of its row from ET
    {
        int row = t0 >> 1, seg = t0 & 1;
        const float4* ep = (const float4*)(ET + (size_t)bk[row] * D + seg * 32);
        float4* op = (float4*)(out + (size_t)(base + row) * D + seg * 32);
        #pragma unroll
        for (int q = 0; q < 8; ++q) op[q] = ep[q];
    }
}

extern "C" void kernel_launch(void* const* d_in, const int* in_sizes, int n_in,
                              void* d_out, int out_size, void* d_ws, size_t ws_size,
                              hipStream_t stream) {
    const float* x = (const float*)d_in[0];
    const float* E = (const float*)d_in[1];
    float* out = (float*)d_out;
    int N = in_sizes[0] / D;   // 131072

    // ws: e_sq64 8K | e_sq32 4K | ET 256K | Bhi 128K | Blo 128K
    char* w = (char*)d_ws;
    double*         e_sq64 = (double*)w;          w += K * sizeof(double);
    float*          e_sq32 = (float*)w;           w += K * sizeof(float);
    float*          ET     = (float*)w;           w += (size_t)K * D * sizeof(float);
    unsigned short* Bhi    = (unsigned short*)w;  w += (size_t)K * D * sizeof(unsigned short);
    unsigned short* Blo    = (unsigned short*)w;  w += (size_t)K * D * sizeof(unsigned short);

    vq_prep<<<256, 256, 0, stream>>>(E, e_sq64, e_sq32, ET, Bhi, Blo);
    vq_screen<<<N / 128, 256, 0, stream>>>(x, Bhi, Blo,
                                           e_sq32, e_sq64, ET, out);
}

// Round 6
// 172.420 us; speedup vs baseline: 1.0087x; 1.0087x over previous
//
#include <hip/hip_runtime.h>
#include <hip/hip_bf16.h>
#include <stdint.h>

// VQ: x [N=131072, D=64] fp32, E [D=64, K=1024] fp32.
// R11: wave-PRIVATE LDS staging, zero in-loop barriers. R10 failed because
// __syncthreads() drains vmcnt(0) -> per-tile barrier made staging synchronous
// (the documented m97 barrier-drain stall). Fix: each wave stages the FULL
// 4KB B tile into its own double buffer (Bst[wid][2][2048], 32KB total) with
// 4x global_load_lds(16B); buffer safety is wave-local (frags register-held
// before overwrite), so the 64-tile loop has NO barriers. Completion via
// counted inline-asm s_waitcnt vmcnt(4) (never 0, T4 pattern — valid per-wave).
// ds_read of tile t+1 issues right after the vmcnt and is consumed next
// half-body -> LDS latency overlaps min-update. Manual 2x unroll keeps all
// indices compile-time. Screen math + fused fp64 refine identical to R8-R10.
// Verified facts used: A[m=lane&15][k=(lane>>4)*8+j] (m89/m91/m120),
// C/D col=lane&15 row=(lane>>4)*4+reg (m89/m91), frag types short8/float4.

typedef unsigned long long u64;
typedef short short8 __attribute__((ext_vector_type(8)));
typedef float f32x4 __attribute__((ext_vector_type(4)));

constexpr int D = 64;
constexpr int K = 1024;
constexpr float TAU = 1e-3f;

__device__ __forceinline__ unsigned short bf16_rne(float v) {
    uint32_t u = __float_as_uint(v);
    uint32_t r = u + 0x7FFFu + ((u >> 16) & 1u);
    return (unsigned short)(r >> 16);
}
__device__ __forceinline__ float bf16_f(unsigned short h) {
    return __uint_as_float(((uint32_t)h) << 16);
}
// monotone fp32 -> u32 map (min preserved) — R3-proven
__device__ __forceinline__ uint32_t fmap(float v) {
    uint32_t u = __float_as_uint(v);
    return (u & 0x80000000u) ? ~u : (u | 0x80000000u);
}
__device__ __forceinline__ float funmap(uint32_t m) {
    uint32_t u = (m & 0x80000000u) ? (m ^ 0x80000000u) : ~m;
    return __uint_as_float(u);
}
__device__ __forceinline__ void top2_merge(u64& b, u64& s, u64 ob, u64 os) {
    if (ob < b) { s = (b < os) ? b : os; b = ob; }
    else        { s = (ob < s) ? ob : s; }
}
__device__ __forceinline__ u64 shfl_xor_u64(u64 v, int m) {
    uint32_t lo = (uint32_t)v, hi = (uint32_t)(v >> 32);
    lo = (uint32_t)__shfl_xor((int)lo, m, 64);
    hi = (uint32_t)__shfl_xor((int)hi, m, 64);
    return ((u64)hi << 32) | lo;
}
__device__ __forceinline__ double shfl_xor_f64(double v, int m) {
    int lo = __double2loint(v), hi = __double2hiint(v);
    lo = __shfl_xor(lo, m, 64);
    hi = __shfl_xor(hi, m, 64);
    return __hiloint2double(hi, lo);
}
// 8 fp32 -> bf16 hi + residual-lo fragments (in-register, no LDS transpose)
__device__ __forceinline__ void cvt8(float4 a, float4 b, short8& H, short8& L) {
    float v[8] = {a.x, a.y, a.z, a.w, b.x, b.y, b.z, b.w};
    #pragma unroll
    for (int e = 0; e < 8; ++e) {
        unsigned short h = bf16_rne(v[e]);
        H[e] = (short)h;
        L[e] = (short)bf16_rne(v[e] - bf16_f(h));
    }
}

// ---- prep: e_sq (f64/f32), ET[k][d] gather table, Bhi/Blo fragment-linear
//      bf16 tables of -2E (hi + residual lo). grid 256 x 256. ----
__global__ __launch_bounds__(256) void vq_prep(const float* __restrict__ E,
                                               double* __restrict__ e_sq64,
                                               float* __restrict__ e_sq32,
                                               float* __restrict__ ET,
                                               unsigned short* __restrict__ Bhi,
                                               unsigned short* __restrict__ Blo) {
    int tid = blockIdx.x * 256 + threadIdx.x;        // 0..65535
    if (tid < K) {
        int k = tid;
        double s = 0.0;
        for (int d = 0; d < D; ++d) {
            float v = E[d * K + k];
            s = fma((double)v, (double)v, s);
            ET[k * D + d] = v;
        }
        e_sq64[k] = s;
        e_sq32[k] = (float)s;
    }
    // table entry: frag f = t*2+c (t=tile 0..63, c=k-chunk 0..1), lane l, slot j
    //   value = -2*E[d][code], d = 32c + 8*(l>>4) + j, code = 16t + (l&15)
    //   linear: tile t owns shorts [t*1024, t*1024+1024), chunk c at +c*512,
    //   lane l at +l*8 — 4KB/tile contiguous across Bhi+Blo.
    {
        int j = tid & 7;
        int l = (tid >> 3) & 63;
        int f = tid >> 9;            // 0..127
        int c = f & 1;
        int t = f >> 1;
        int d = 32 * c + 8 * (l >> 4) + j;
        int code = 16 * t + (l & 15);
        float v = -2.0f * E[d * K + code];
        unsigned short h = bf16_rne(v);
        Bhi[tid] = h;
        Blo[tid] = bf16_rne(v - bf16_f(h));
    }
}

// ---- screen + fused exact refine: block = 128 rows (4 waves x 32) ----
__global__ __launch_bounds__(256, 4) void vq_screen(
    const float* __restrict__ x,
    const unsigned short* __restrict__ Bhi, const unsigned short* __restrict__ Blo,
    const float* __restrict__ e_sq32, const double* __restrict__ e_sq64,
    const float* __restrict__ ET, float* __restrict__ out) {
    __shared__ float esq[K];                   // 4 KB
    __shared__ unsigned short Bst[4][2][2048]; // 32 KB: per-wave private dbuf
    __shared__ int bk[128];                    // 0.5 KB
    __shared__ double xs64[D];                 // 0.5 KB (refine staging)
    __shared__ double wbv[4];
    __shared__ int wbk_s[4];
    __shared__ int flag_list[128];             // 0.5 KB
    __shared__ int flag_n;

    const int t0 = threadIdx.x;
    const int base = blockIdx.x * 128;

    if (t0 == 0) flag_n = 0;

    // stage e_sq
    #pragma unroll
    for (int i = 0; i < 4; ++i) esq[i * 256 + t0] = e_sq32[i * 256 + t0];

    const int wid = t0 >> 6, l = t0 & 63;
    const int col = l & 15, quad = l >> 4;

    // wave-private full-tile staging: 4 x 16B/lane = 4KB tile into own buffer.
    // LDS dst base wave-uniform (+lane*16 by HW); global src per-lane (m104).
    #define STAGE4(tile, buf) do {                                               \
        const unsigned short* _sh = Bhi + (tile) * 1024 + (l << 3);              \
        const unsigned short* _sl = Blo + (tile) * 1024 + (l << 3);              \
        __builtin_amdgcn_global_load_lds(                                        \
            (const __attribute__((address_space(1))) void*)(_sh),                \
            (__attribute__((address_space(3))) void*)&Bst[wid][buf][0], 16,0,0); \
        __builtin_amdgcn_global_load_lds(                                        \
            (const __attribute__((address_space(1))) void*)(_sh + 512),          \
            (__attribute__((address_space(3))) void*)&Bst[wid][buf][512], 16,0,0);\
        __builtin_amdgcn_global_load_lds(                                        \
            (const __attribute__((address_space(1))) void*)(_sl),                \
            (__attribute__((address_space(3))) void*)&Bst[wid][buf][1024],16,0,0);\
        __builtin_amdgcn_global_load_lds(                                        \
            (const __attribute__((address_space(1))) void*)(_sl + 512),          \
            (__attribute__((address_space(3))) void*)&Bst[wid][buf][1536],16,0,0);\
    } while (0)

    // A fragments for 2 rowsets, loaded DIRECTLY from global in fragment order
    // (verified layout: m = lane&15, k = quad*8 + j, k-chunks at 0 and 32).
    const int gr0 = base + wid * 32 + col;     // rowset a global row
    short8 Ah0a, Ah1a, Al0a, Al1a, Ah0b, Ah1b, Al0b, Al1b;
    {
        const float* xr = x + (size_t)gr0 * D + quad * 8;
        float4 p0 = *(const float4*)(xr);
        float4 p1 = *(const float4*)(xr + 4);
        float4 p2 = *(const float4*)(xr + 32);
        float4 p3 = *(const float4*)(xr + 36);
        const float* xs = xr + 16 * D;         // rowset b
        float4 q0 = *(const float4*)(xs);
        float4 q1 = *(const float4*)(xs + 4);
        float4 q2 = *(const float4*)(xs + 32);
        float4 q3 = *(const float4*)(xs + 36);
        cvt8(p0, p1, Ah0a, Al0a);
        cvt8(p2, p3, Ah1a, Al1a);
        cvt8(q0, q1, Ah0b, Al0b);
        cvt8(q2, q3, Ah1b, Al1b);
    }

    float besta[4], seca[4], bestb[4], secb[4];
    int bidxa[4], bidxb[4];
    #pragma unroll
    for (int r = 0; r < 4; ++r) {
        besta[r] = 3.4e38f; seca[r] = 3.4e38f; bidxa[r] = 0;
        bestb[r] = 3.4e38f; secb[r] = 3.4e38f; bidxb[r] = 0;
    }

    // MFMA + min-update for one tile, frags passed explicitly (compile-time regs)
    #define TILE_BODY(tt, fh0, fh1, fl0, fl1)                                    \
    do {                                                                         \
        float esv = esq[(tt) * 16 + col];                                        \
        f32x4 Ca = {esv, esv, esv, esv};                                         \
        f32x4 Cb = {esv, esv, esv, esv};                                         \
        Ca = __builtin_amdgcn_mfma_f32_16x16x32_bf16(Ah0a, fh0, Ca, 0, 0, 0);    \
        Cb = __builtin_amdgcn_mfma_f32_16x16x32_bf16(Ah0b, fh0, Cb, 0, 0, 0);    \
        Ca = __builtin_amdgcn_mfma_f32_16x16x32_bf16(Ah1a, fh1, Ca, 0, 0, 0);    \
        Cb = __builtin_amdgcn_mfma_f32_16x16x32_bf16(Ah1b, fh1, Cb, 0, 0, 0);    \
        Ca = __builtin_amdgcn_mfma_f32_16x16x32_bf16(Ah0a, fl0, Ca, 0, 0, 0);    \
        Cb = __builtin_amdgcn_mfma_f32_16x16x32_bf16(Ah0b, fl0, Cb, 0, 0, 0);    \
        Ca = __builtin_amdgcn_mfma_f32_16x16x32_bf16(Ah1a, fl1, Ca, 0, 0, 0);    \
        Cb = __builtin_amdgcn_mfma_f32_16x16x32_bf16(Ah1b, fl1, Cb, 0, 0, 0);    \
        Ca = __builtin_amdgcn_mfma_f32_16x16x32_bf16(Al0a, fh0, Ca, 0, 0, 0);    \
        Cb = __builtin_amdgcn_mfma_f32_16x16x32_bf16(Al0b, fh0, Cb, 0, 0, 0);    \
        Ca = __builtin_amdgcn_mfma_f32_16x16x32_bf16(Al1a, fh1, Ca, 0, 0, 0);    \
        Cb = __builtin_amdgcn_mfma_f32_16x16x32_bf16(Al1b, fh1, Cb, 0, 0, 0);    \
        int tc = (tt) * 16;                                                      \
        _Pragma("unroll")                                                        \
        for (int r = 0; r < 4; ++r) {                                            \
            float va = Ca[r];                                                    \
            bool lta = va < besta[r];                                            \
            float mxa = fmaxf(va, besta[r]);                                     \
            besta[r] = fminf(va, besta[r]);                                      \
            seca[r]  = fminf(seca[r], mxa);                                      \
            bidxa[r] = lta ? tc : bidxa[r];                                      \
            float vb = Cb[r];                                                    \
            bool ltb = vb < bestb[r];                                            \
            float mxb = fmaxf(vb, bestb[r]);                                     \
            bestb[r] = fminf(vb, bestb[r]);                                      \
            secb[r]  = fminf(secb[r], mxb);                                      \
            bidxb[r] = ltb ? tc : bidxb[r];                                      \
        }                                                                        \
    } while (0)

    #define LOAD_FRAGS(buf, fh0, fh1, fl0, fl1)                                  \
        fh0 = *(const short8*)&Bst[wid][buf][l * 8];                             \
        fh1 = *(const short8*)&Bst[wid][buf][512 + l * 8];                       \
        fl0 = *(const short8*)&Bst[wid][buf][1024 + l * 8];                      \
        fl1 = *(const short8*)&Bst[wid][buf][1536 + l * 8]

    // prologue: tile 0 -> buf0; the one barrier (esq visibility) also drains it
    STAGE4(0, 0);
    __syncthreads();
    short8 ch0, ch1, cl0, cl1, nh0, nh1, nl0, nl1;
    LOAD_FRAGS(0, ch0, ch1, cl0, cl1);         // tile 0 frags
    STAGE4(1, 1);                              // 4 ops in flight

    for (int t = 0; t < 64; t += 2) {
        // ---- even tile t: frags in c*, buf0 holds tile t ----
        TILE_BODY(t, ch0, ch1, cl0, cl1);
        __builtin_amdgcn_sched_barrier(0);     // c* consumed before overwrite
        STAGE4((t + 2) & 63, 0);               // tile t+2 -> buf0 (8 in flight)
        asm volatile("s_waitcnt vmcnt(4)" ::: "memory");  // tile t+1 landed
        __builtin_amdgcn_sched_barrier(0);
        LOAD_FRAGS(1, nh0, nh1, nl0, nl1);     // tile t+1 frags (consumed below)

        // ---- odd tile t+1: frags in n*, buf1 holds tile t+1 ----
        TILE_BODY(t + 1, nh0, nh1, nl0, nl1);
        __builtin_amdgcn_sched_barrier(0);
        STAGE4((t + 3) & 63, 1);               // tile t+3 -> buf1
        asm volatile("s_waitcnt vmcnt(4)" ::: "memory");  // tile t+2 landed
        __builtin_amdgcn_sched_barrier(0);
        LOAD_FRAGS(0, ch0, ch1, cl0, cl1);     // tile t+2 frags
    }
    #undef STAGE4
    #undef TILE_BODY
    #undef LOAD_FRAGS

    // per-register reduce across the 16 col-lanes (masks 1..8 preserve quad)
    #pragma unroll
    for (int r = 0; r < 4; ++r) {
        {   // rowset a
            u64 b = ((u64)fmap(besta[r]) << 32) | (uint32_t)(bidxa[r] + col);
            u64 s = ((u64)fmap(seca[r]) << 32) | 0xFFFFFFFFu;
            #pragma unroll
            for (int m = 8; m >= 1; m >>= 1) {
                u64 ob = shfl_xor_u64(b, m);
                u64 os = shfl_xor_u64(s, m);
                top2_merge(b, s, ob, os);
            }
            if (col == 0) {
                int rowL = wid * 32 + quad * 4 + r;       // verified C row map
                bk[rowL] = (int)(uint32_t)(b & 0xFFFFFFFFu);
                float vb = funmap((uint32_t)(b >> 32));
                float vs = funmap((uint32_t)(s >> 32));
                if (vs - vb < TAU) {
                    int idx = atomicAdd(&flag_n, 1);
                    flag_list[idx] = rowL;
                }
            }
        }
        {   // rowset b
            u64 b = ((u64)fmap(bestb[r]) << 32) | (uint32_t)(bidxb[r] + col);
            u64 s = ((u64)fmap(secb[r]) << 32) | 0xFFFFFFFFu;
            #pragma unroll
            for (int m = 8; m >= 1; m >>= 1) {
                u64 ob = shfl_xor_u64(b, m);
                u64 os = shfl_xor_u64(s, m);
                top2_merge(b, s, ob, os);
            }
            if (col == 0) {
                int rowL = wid * 32 + 16 + quad * 4 + r;
                bk[rowL] = (int)(uint32_t)(b & 0xFFFFFFFFu);
                float vb = funmap((uint32_t)(b >> 32));
                float vs = funmap((uint32_t)(s >> 32));
                if (vs - vb < TAU) {
                    int idx = atomicAdd(&flag_n, 1);
                    flag_list[idx] = rowL;
                }
            }
        }
    }
    __syncthreads();

    // fused exact refine for flagged rows (rare: ~0.03 rows/block expected).
    // Identical math + tie-breaks to the proven vq_refine kernel:
    // ET[k*D+d] == E[d*K+k] exactly; fp64 fma over ascending d; v<best with
    // ascending k; wave reduce then cross-wave lowest-k-on-tie merge.
    {
        int nf = flag_n;                         // uniform across block
        for (int f = 0; f < nf; ++f) {
            int rowR = flag_list[f];
            if (t0 < D) xs64[t0] = (double)x[(size_t)(base + rowR) * D + t0];
            __syncthreads();
            double best = 1.0e300; int bestk = 0;
            #pragma unroll
            for (int j = 0; j < 4; ++j) {
                int k = t0 * 4 + j;
                const float* ep = ET + (size_t)k * D;
                double a = 0.0;
                #pragma unroll 4
                for (int d = 0; d < D; ++d)
                    a = fma(xs64[d], (double)ep[d], a);
                double v = fma(-2.0, a, e_sq64[k]);
                if (v < best) { best = v; bestk = k; }
            }
            #pragma unroll
            for (int m = 32; m >= 1; m >>= 1) {
                double ov = shfl_xor_f64(best, m);
                int    ok = __shfl_xor(bestk, m, 64);
                if (ov < best || (ov == best && ok < bestk)) { best = ov; bestk = ok; }
            }
            if ((t0 & 63) == 0) { wbv[t0 >> 6] = best; wbk_s[t0 >> 6] = bestk; }
            __syncthreads();
            if (t0 == 0) {
                double bv = wbv[0]; int bb = wbk_s[0];
                for (int w = 1; w < 4; ++w)
                    if (wbv[w] < bv || (wbv[w] == bv && wbk_s[w] < bb)) { bv = wbv[w]; bb = wbk_s[w]; }
                bk[rowR] = bb;
            }
            __syncthreads();
        }
    }

    // gather: thread t0 copies 128 B of its row from ET
    {
        int row = t0 >> 1, seg = t0 & 1;
        const float4* ep = (const float4*)(ET + (size_t)bk[row] * D + seg * 32);
        float4* op = (float4*)(out + (size_t)(base + row) * D + seg * 32);
        #pragma unroll
        for (int q = 0; q < 8; ++q) op[q] = ep[q];
    }
}

extern "C" void kernel_launch(void* const* d_in, const int* in_sizes, int n_in,
                              void* d_out, int out_size, void* d_ws, size_t ws_size,
                              hipStream_t stream) {
    const float* x = (const float*)d_in[0];
    const float* E = (const float*)d_in[1];
    float* out = (float*)d_out;
    int N = in_sizes[0] / D;   // 131072

    // ws: e_sq64 8K | e_sq32 4K | ET 256K | Bhi 128K | Blo 128K
    char* w = (char*)d_ws;
    double*         e_sq64 = (double*)w;          w += K * sizeof(double);
    float*          e_sq32 = (float*)w;           w += K * sizeof(float);
    float*          ET     = (float*)w;           w += (size_t)K * D * sizeof(float);
    unsigned short* Bhi    = (unsigned short*)w;  w += (size_t)K * D * sizeof(unsigned short);
    unsigned short* Blo    = (unsigned short*)w;  w += (size_t)K * D * sizeof(unsigned short);

    vq_prep<<<256, 256, 0, stream>>>(E, e_sq64, e_sq32, ET, Bhi, Blo);
    vq_screen<<<N / 128, 256, 0, stream>>>(x, Bhi, Blo,
                                           e_sq32, e_sq64, ET, out);
}